// Round 4
// baseline (127.693 us; speedup 1.0000x reference)
//
#include <hip/hip_runtime.h>
#include <stdint.h>

#define D_ 384
#define NPTS 4096

// ---------------- Threefry-2x32 (JAX-exact, 20 rounds) ----------------
__device__ __forceinline__ void tf_round(uint32_t& x0, uint32_t& x1, int r) {
  x0 += x1;
  x1 = (x1 << r) | (x1 >> (32 - r));
  x1 ^= x0;
}

__device__ void tf2x32(uint32_t k0, uint32_t k1, uint32_t x0, uint32_t x1,
                       uint32_t& y0, uint32_t& y1) {
  uint32_t ks2 = k0 ^ k1 ^ 0x1BD11BDAu;
  x0 += k0; x1 += k1;
  tf_round(x0, x1, 13); tf_round(x0, x1, 15); tf_round(x0, x1, 26); tf_round(x0, x1, 6);
  x0 += k1; x1 += ks2 + 1u;
  tf_round(x0, x1, 17); tf_round(x0, x1, 29); tf_round(x0, x1, 16); tf_round(x0, x1, 24);
  x0 += ks2; x1 += k0 + 2u;
  tf_round(x0, x1, 13); tf_round(x0, x1, 15); tf_round(x0, x1, 26); tf_round(x0, x1, 6);
  x0 += k0; x1 += k1 + 3u;
  tf_round(x0, x1, 17); tf_round(x0, x1, 29); tf_round(x0, x1, 16); tf_round(x0, x1, 24);
  x0 += k1; x1 += ks2 + 4u;
  tf_round(x0, x1, 13); tf_round(x0, x1, 15); tf_round(x0, x1, 26); tf_round(x0, x1, 6);
  x0 += ks2; x1 += k0 + 5u;
  y0 = x0; y1 = x1;
}

// ---------------- pool16: w16[b][cell][d] = mean of 4x4 block ----------------
// w16 lives at ws+0: [32][256][384] floats (12.6 MB). HBM-bound floor kernel.
__global__ __launch_bounds__(256) void pool16_kernel(const float* __restrict__ feats,
                                                     float* __restrict__ ws) {
  int g = blockIdx.x * 256 + threadIdx.x;
  int q = g % 96;
  int cell = (g / 96) & 255;
  int b = g / (96 * 256);
  int ch = cell >> 4, cw = cell & 15;
  const float* fb = feats + (size_t)b * NPTS * D_;
  float ax = 0.f, ay = 0.f, az = 0.f, aw = 0.f;
  #pragma unroll
  for (int dh = 0; dh < 4; ++dh) {
    int h = ch * 4 + dh;
    #pragma unroll
    for (int dw = 0; dw < 4; ++dw) {
      int w = cw * 4 + dw;
      float4 v = *(const float4*)(fb + ((size_t)(h * 64 + w)) * D_ + q * 4);
      ax += v.x; ay += v.y; az += v.z; aw += v.w;
    }
  }
  float4 o = { ax * (1.f/16.f), ay * (1.f/16.f), az * (1.f/16.f), aw * (1.f/16.f) };
  *(float4*)(ws + ((size_t)(b * 256 + cell)) * D_ + q * 4) = o;
}

// ---------------- fused k-means++ (derives its own pooled tier from w16) ----------------
// 96 blocks (si = blk/32, b = blk%32), 512 threads; 2 threads per row hold the
// row in registers (48 float4 each). si=1/si=0 pooled rows are computed from
// w16 with bit-identical association to the old pool8/pool4 kernels.
__global__ __launch_bounds__(512) void kmeans_kernel(const float* __restrict__ ws,
                                                     float* __restrict__ out) {
  int blk = blockIdx.x;
  int si = blk / 32;
  int b  = blk % 32;
  int n  = (si == 0) ? 16 : (si == 1) ? 64 : 256;

  const float4* w16b = (const float4*)(ws + (size_t)b * 256 * D_);  // [cell*96 + q]
  float* ob = out + ((size_t)b * 12 + si * 4) * D_;

  __shared__ __align__(16) float4 p4buf[16 * 96];   // si=0 staging (24 KB)
  __shared__ __align__(16) float4 csh4[96];         // current center row
  __shared__ float minsq[256];
  __shared__ uint32_t skey[3][2];
  __shared__ int sidx;
  __shared__ float ssum;
  __shared__ float wred[4];
  __shared__ float wmaxv[4];
  __shared__ int   wmaxi[4];

  int tid  = threadIdx.x;
  int row  = tid >> 1;        // 0..255
  int part = tid & 1;         // half-row owner
  int lane = tid & 63;
  int wv   = tid >> 6;

  if (tid == 0) {
    // base = key(42); folded = fold_in(base, si); bkey = split(folded,32)[b]
    uint32_t f0, f1, bk0, bk1;
    tf2x32(0u, 42u, 0u, (uint32_t)si, f0, f1);
    tf2x32(f0, f1, 0u, (uint32_t)b, bk0, bk1);
    uint32_t k00, k01, k10, k11;
    tf2x32(bk0, bk1, 0u, 0u, k00, k01);     // k0 = split(bkey)[0]
    tf2x32(bk0, bk1, 0u, 1u, k10, k11);     // k1 = split(bkey)[1]
    // randint(k0,(),0,n): _, kk2 = split(k0); lower = bits(kk2); idx = lower % n
    uint32_t q0, q1, l0, l1;
    tf2x32(k00, k01, 0u, 1u, q0, q1);
    tf2x32(q0, q1, 0u, 0u, l0, l1);
    sidx = (int)((l0 ^ l1) & (uint32_t)(n - 1));
    for (int t = 0; t < 3; ++t) {           // step keys = split(k1, 3)
      uint32_t a, bb;
      tf2x32(k10, k11, 0u, (uint32_t)t, a, bb);
      skey[t][0] = a; skey[t][1] = bb;
    }
  }
  if (tid < 256) minsq[tid] = 0.f;

  // ---- build this thread's half-row xr[48] in registers ----
  float4 xr[48];
  if (si == 2) {
    const float4* rp = w16b + (size_t)row * 96 + part * 48;
    #pragma unroll 8
    for (int k = 0; k < 48; ++k) xr[k] = rp[k];
  } else if (si == 1) {
    if (row < 64) {
      int p = row >> 3, r = row & 7;
      int c00 = (p * 2) * 16 + (r * 2);
      const float4* r00 = w16b + (size_t)c00 * 96 + part * 48;        // (a=0,c=0)
      const float4* r01 = w16b + (size_t)(c00 + 1) * 96 + part * 48;  // (0,1)
      const float4* r10 = w16b + (size_t)(c00 + 16) * 96 + part * 48; // (1,0)
      const float4* r11 = w16b + (size_t)(c00 + 17) * 96 + part * 48; // (1,1)
      #pragma unroll 4
      for (int k = 0; k < 48; ++k) {
        float4 v0 = r00[k], v1 = r01[k], v2 = r10[k], v3 = r11[k];
        float4 o;
        o.x = (((v0.x + v1.x) + v2.x) + v3.x) * 0.25f;
        o.y = (((v0.y + v1.y) + v2.y) + v3.y) * 0.25f;
        o.z = (((v0.z + v1.z) + v2.z) + v3.z) * 0.25f;
        o.w = (((v0.w + v1.w) + v2.w) + v3.w) * 0.25f;
        xr[k] = o;
      }
    }
  } else {
    // si=0: all 512 threads stage the 16 w4 rows into LDS,
    // replicating pool8 -> pool4 association exactly.
    int r4 = tid >> 5;          // output row 0..15
    int sub = tid & 31;
    int p = r4 >> 2, r = r4 & 3;
    for (int it = 0; it < 3; ++it) {
      int q = sub + it * 32;    // 0..95
      float ax = 0.f, ay = 0.f, az = 0.f, aw = 0.f;   // w4 accum (starts at 0, like pool4)
      #pragma unroll
      for (int a = 0; a < 2; ++a)
        #pragma unroll
        for (int c = 0; c < 2; ++c) {
          int p8 = p * 2 + a, r8 = r * 2 + c;
          float bx = 0.f, by = 0.f, bz = 0.f, bw = 0.f; // w8 accum (starts at 0, like pool8)
          #pragma unroll
          for (int a2 = 0; a2 < 2; ++a2)
            #pragma unroll
            for (int c2 = 0; c2 < 2; ++c2) {
              int cell = (p8 * 2 + a2) * 16 + (r8 * 2 + c2);
              float4 v = w16b[(size_t)cell * 96 + q];
              bx += v.x; by += v.y; bz += v.z; bw += v.w;
            }
          bx *= 0.25f; by *= 0.25f; bz *= 0.25f; bw *= 0.25f;
          ax += bx; ay += by; az += bz; aw += bw;
        }
      float4 o = { ax * 0.25f, ay * 0.25f, az * 0.25f, aw * 0.25f };
      p4buf[r4 * 96 + q] = o;
    }
    __syncthreads();            // block-uniform branch: legal
    if (row < 16) {
      #pragma unroll 8
      for (int k = 0; k < 48; ++k) xr[k] = p4buf[row * 96 + part * 48 + k];
    }
  }
  __syncthreads();   // sidx + minsq + xr ready

  // c0: owners write their registers to LDS + output slot 0
  if (row == sidx) {
    float4* cb = csh4 + part * 48;
    float4* op = (float4*)(ob + part * 192);
    #pragma unroll
    for (int k = 0; k < 48; ++k) { cb[k] = xr[k]; op[k] = xr[k]; }
  }
  __syncthreads();

  // min_sq = ||x - c0||^2
  if (row < n) {
    float acc = 0.f;
    #pragma unroll
    for (int k = 0; k < 48; ++k) {
      float4 c4 = csh4[part * 48 + k];
      float dx = xr[k].x - c4.x, dy = xr[k].y - c4.y;
      float dz = xr[k].z - c4.z, dw = xr[k].w - c4.w;
      acc += dx * dx; acc += dy * dy; acc += dz * dz; acc += dw * dw;
    }
    acc += __shfl_xor(acc, 1);              // combine the 2 half-rows
    if (part == 0) minsq[row] = acc;
  }
  __syncthreads();

  const float TINY = __uint_as_float(0x00800000u);  // f32 tiny

  for (int t = 0; t < 3; ++t) {
    // --- parallel sum(min_sq) over 256 slots (zeros pad) ---
    if (tid < 256) {
      float v = minsq[tid];
      #pragma unroll
      for (int m = 1; m < 64; m <<= 1) v += __shfl_xor(v, m);
      if (lane == 0) wred[wv] = v;
    }
    __syncthreads();
    if (tid == 0) ssum = ((wred[0] + wred[1]) + (wred[2] + wred[3])) + 1e-8f;
    __syncthreads();

    // --- z_i = gumbel_i + log(prob_i + 1e-12); argmax (first occurrence) ---
    if (tid < 256) {
      float z = -1e30f;
      if (tid < n) {
        float prob  = minsq[tid] / ssum;
        float logit = logf(prob + 1e-12f);
        uint32_t y0, y1;
        tf2x32(skey[t][0], skey[t][1], 0u, (uint32_t)tid, y0, y1);
        uint32_t bits = y0 ^ y1;
        float f = __uint_as_float((bits >> 9) | 0x3F800000u) - 1.0f;
        float u = (f > 0.f) ? f : TINY;
        z = -logf(-logf(u)) + logit;
      }
      float bv = z; int bi = tid;
      #pragma unroll
      for (int m = 1; m < 64; m <<= 1) {
        float ov = __shfl_xor(bv, m);
        int   oi = __shfl_xor(bi, m);
        if (ov > bv || (ov == bv && oi < bi)) { bv = ov; bi = oi; }
      }
      if (lane == 0) { wmaxv[wv] = bv; wmaxi[wv] = bi; }
    }
    __syncthreads();
    if (tid == 0) {
      float cv = wmaxv[0]; int ci = wmaxi[0];
      for (int w2 = 1; w2 < 4; ++w2)
        if (wmaxv[w2] > cv || (wmaxv[w2] == cv && wmaxi[w2] < ci)) { cv = wmaxv[w2]; ci = wmaxi[w2]; }
      sidx = ci;
    }
    __syncthreads();

    // --- new center from owners' registers -> LDS + out ---
    if (row == sidx) {
      float4* cb = csh4 + part * 48;
      float4* op = (float4*)(ob + (size_t)(t + 1) * D_ + part * 192);
      #pragma unroll
      for (int k = 0; k < 48; ++k) { cb[k] = xr[k]; op[k] = xr[k]; }
    }
    __syncthreads();

    // --- min_sq = min(min_sq, ||x - c||^2) ---
    if (row < n) {
      float acc = 0.f;
      #pragma unroll
      for (int k = 0; k < 48; ++k) {
        float4 c4 = csh4[part * 48 + k];
        float dx = xr[k].x - c4.x, dy = xr[k].y - c4.y;
        float dz = xr[k].z - c4.z, dw = xr[k].w - c4.w;
        acc += dx * dx; acc += dy * dy; acc += dz * dz; acc += dw * dw;
      }
      acc += __shfl_xor(acc, 1);
      if (part == 0) minsq[row] = fminf(minsq[row], acc);
    }
    __syncthreads();
  }
}

extern "C" void kernel_launch(void* const* d_in, const int* in_sizes, int n_in,
                              void* d_out, int out_size, void* d_ws, size_t ws_size,
                              hipStream_t stream) {
  const float* feats = (const float*)d_in[0];
  float* out = (float*)d_out;
  float* ws  = (float*)d_ws;   // uses 12,582,912 bytes (w16 only)

  pool16_kernel<<<3072, 256, 0, stream>>>(feats, ws);
  kmeans_kernel<<<96, 512, 0, stream>>>(ws, out);
}

// Round 5
// 74.488 us; speedup vs baseline: 1.7143x; 1.7143x over previous
//
#include <hip/hip_runtime.h>
#include <stdint.h>

#define D_ 384
#define NPTS 4096

// ---------------- Threefry-2x32 (JAX-exact, 20 rounds) ----------------
__device__ __forceinline__ void tf_round(uint32_t& x0, uint32_t& x1, int r) {
  x0 += x1;
  x1 = (x1 << r) | (x1 >> (32 - r));
  x1 ^= x0;
}

__device__ void tf2x32(uint32_t k0, uint32_t k1, uint32_t x0, uint32_t x1,
                       uint32_t& y0, uint32_t& y1) {
  uint32_t ks2 = k0 ^ k1 ^ 0x1BD11BDAu;
  x0 += k0; x1 += k1;
  tf_round(x0, x1, 13); tf_round(x0, x1, 15); tf_round(x0, x1, 26); tf_round(x0, x1, 6);
  x0 += k1; x1 += ks2 + 1u;
  tf_round(x0, x1, 17); tf_round(x0, x1, 29); tf_round(x0, x1, 16); tf_round(x0, x1, 24);
  x0 += ks2; x1 += k0 + 2u;
  tf_round(x0, x1, 13); tf_round(x0, x1, 15); tf_round(x0, x1, 26); tf_round(x0, x1, 6);
  x0 += k0; x1 += k1 + 3u;
  tf_round(x0, x1, 17); tf_round(x0, x1, 29); tf_round(x0, x1, 16); tf_round(x0, x1, 24);
  x0 += k1; x1 += ks2 + 4u;
  tf_round(x0, x1, 13); tf_round(x0, x1, 15); tf_round(x0, x1, 26); tf_round(x0, x1, 6);
  x0 += ks2; x1 += k0 + 5u;
  y0 = x0; y1 = x1;
}

// ---------------- pool16: w16[b][cell][d] = mean of 4x4 block ----------------
// w16 lives at ws+0: [32][256][384] floats (12.6 MB). HBM-bound floor kernel.
__global__ __launch_bounds__(256) void pool16_kernel(const float* __restrict__ feats,
                                                     float* __restrict__ ws) {
  int g = blockIdx.x * 256 + threadIdx.x;
  int q = g % 96;
  int cell = (g / 96) & 255;
  int b = g / (96 * 256);
  int ch = cell >> 4, cw = cell & 15;
  const float* fb = feats + (size_t)b * NPTS * D_;
  float ax = 0.f, ay = 0.f, az = 0.f, aw = 0.f;
  #pragma unroll
  for (int dh = 0; dh < 4; ++dh) {
    int h = ch * 4 + dh;
    #pragma unroll
    for (int dw = 0; dw < 4; ++dw) {
      int w = cw * 4 + dw;
      float4 v = *(const float4*)(fb + ((size_t)(h * 64 + w)) * D_ + q * 4);
      ax += v.x; ay += v.y; az += v.z; aw += v.w;
    }
  }
  float4 o = { ax * (1.f/16.f), ay * (1.f/16.f), az * (1.f/16.f), aw * (1.f/16.f) };
  *(float4*)(ws + ((size_t)(b * 256 + cell)) * D_ + q * 4) = o;
}

// ---------------- fused k-means++ (derives its own pooled tier from w16) ----------------
// 96 blocks (si = blk/32, b = blk%32), 512 threads; 2 threads per row hold the
// row in registers (48 float4 each). ALL loops indexing xr[] MUST be fully
// unrolled (#pragma unroll, no count) — partial unroll -> runtime index ->
// xr spills to scratch (rule #20; this was round 4's 2x regression).
__global__ __launch_bounds__(512) void kmeans_kernel(const float* __restrict__ ws,
                                                     float* __restrict__ out) {
  int blk = blockIdx.x;
  int si = blk / 32;
  int b  = blk % 32;
  int n  = (si == 0) ? 16 : (si == 1) ? 64 : 256;

  const float4* w16b = (const float4*)(ws + (size_t)b * 256 * D_);  // [cell*96 + q]
  float* ob = out + ((size_t)b * 12 + si * 4) * D_;

  __shared__ __align__(16) float4 p4buf[16 * 96];   // si=0 staging (24 KB)
  __shared__ __align__(16) float4 csh4[96];         // current center row
  __shared__ float minsq[256];
  __shared__ uint32_t skey[3][2];
  __shared__ int sidx;
  __shared__ float ssum;
  __shared__ float wred[4];
  __shared__ float wmaxv[4];
  __shared__ int   wmaxi[4];

  int tid  = threadIdx.x;
  int row  = tid >> 1;        // 0..255
  int part = tid & 1;         // half-row owner
  int lane = tid & 63;
  int wv   = tid >> 6;

  if (tid == 0) {
    // base = key(42); folded = fold_in(base, si); bkey = split(folded,32)[b]
    uint32_t f0, f1, bk0, bk1;
    tf2x32(0u, 42u, 0u, (uint32_t)si, f0, f1);
    tf2x32(f0, f1, 0u, (uint32_t)b, bk0, bk1);
    uint32_t k00, k01, k10, k11;
    tf2x32(bk0, bk1, 0u, 0u, k00, k01);     // k0 = split(bkey)[0]
    tf2x32(bk0, bk1, 0u, 1u, k10, k11);     // k1 = split(bkey)[1]
    // randint(k0,(),0,n): _, kk2 = split(k0); lower = bits(kk2); idx = lower % n
    uint32_t q0, q1, l0, l1;
    tf2x32(k00, k01, 0u, 1u, q0, q1);
    tf2x32(q0, q1, 0u, 0u, l0, l1);
    sidx = (int)((l0 ^ l1) & (uint32_t)(n - 1));
    for (int t = 0; t < 3; ++t) {           // step keys = split(k1, 3)
      uint32_t a, bb;
      tf2x32(k10, k11, 0u, (uint32_t)t, a, bb);
      skey[t][0] = a; skey[t][1] = bb;
    }
  }
  if (tid < 256) minsq[tid] = 0.f;

  // ---- build this thread's half-row xr[48] in registers ----
  float4 xr[48];
  if (si == 2) {
    const float4* rp = w16b + (size_t)row * 96 + part * 48;
    #pragma unroll
    for (int k = 0; k < 48; ++k) xr[k] = rp[k];
  } else if (si == 1) {
    if (row < 64) {
      int p = row >> 3, r = row & 7;
      int c00 = (p * 2) * 16 + (r * 2);
      const float4* r00 = w16b + (size_t)c00 * 96 + part * 48;        // (a=0,c=0)
      const float4* r01 = w16b + (size_t)(c00 + 1) * 96 + part * 48;  // (0,1)
      const float4* r10 = w16b + (size_t)(c00 + 16) * 96 + part * 48; // (1,0)
      const float4* r11 = w16b + (size_t)(c00 + 17) * 96 + part * 48; // (1,1)
      #pragma unroll
      for (int k = 0; k < 48; ++k) {
        float4 v0 = r00[k], v1 = r01[k], v2 = r10[k], v3 = r11[k];
        float4 o;
        o.x = (((v0.x + v1.x) + v2.x) + v3.x) * 0.25f;
        o.y = (((v0.y + v1.y) + v2.y) + v3.y) * 0.25f;
        o.z = (((v0.z + v1.z) + v2.z) + v3.z) * 0.25f;
        o.w = (((v0.w + v1.w) + v2.w) + v3.w) * 0.25f;
        xr[k] = o;
      }
    }
  } else {
    // si=0: all 512 threads stage the 16 w4 rows into LDS,
    // replicating pool8 -> pool4 association exactly.
    int r4 = tid >> 5;          // output row 0..15
    int sub = tid & 31;
    int p = r4 >> 2, r = r4 & 3;
    for (int it = 0; it < 3; ++it) {
      int q = sub + it * 32;    // 0..95
      float ax = 0.f, ay = 0.f, az = 0.f, aw = 0.f;   // w4 accum (starts at 0, like pool4)
      #pragma unroll
      for (int a = 0; a < 2; ++a)
        #pragma unroll
        for (int c = 0; c < 2; ++c) {
          int p8 = p * 2 + a, r8 = r * 2 + c;
          float bx = 0.f, by = 0.f, bz = 0.f, bw = 0.f; // w8 accum (starts at 0, like pool8)
          #pragma unroll
          for (int a2 = 0; a2 < 2; ++a2)
            #pragma unroll
            for (int c2 = 0; c2 < 2; ++c2) {
              int cell = (p8 * 2 + a2) * 16 + (r8 * 2 + c2);
              float4 v = w16b[(size_t)cell * 96 + q];
              bx += v.x; by += v.y; bz += v.z; bw += v.w;
            }
          bx *= 0.25f; by *= 0.25f; bz *= 0.25f; bw *= 0.25f;
          ax += bx; ay += by; az += bz; aw += bw;
        }
      float4 o = { ax * 0.25f, ay * 0.25f, az * 0.25f, aw * 0.25f };
      p4buf[r4 * 96 + q] = o;
    }
    __syncthreads();            // block-uniform branch: legal
    if (row < 16) {
      #pragma unroll
      for (int k = 0; k < 48; ++k) xr[k] = p4buf[row * 96 + part * 48 + k];
    }
  }
  __syncthreads();   // sidx + minsq + xr ready

  // c0: owners write their registers to LDS + output slot 0
  if (row == sidx) {
    float4* cb = csh4 + part * 48;
    float4* op = (float4*)(ob + part * 192);
    #pragma unroll
    for (int k = 0; k < 48; ++k) { cb[k] = xr[k]; op[k] = xr[k]; }
  }
  __syncthreads();

  // min_sq = ||x - c0||^2
  if (row < n) {
    float acc = 0.f;
    #pragma unroll
    for (int k = 0; k < 48; ++k) {
      float4 c4 = csh4[part * 48 + k];
      float dx = xr[k].x - c4.x, dy = xr[k].y - c4.y;
      float dz = xr[k].z - c4.z, dw = xr[k].w - c4.w;
      acc += dx * dx; acc += dy * dy; acc += dz * dz; acc += dw * dw;
    }
    acc += __shfl_xor(acc, 1);              // combine the 2 half-rows
    if (part == 0) minsq[row] = acc;
  }
  __syncthreads();

  const float TINY = __uint_as_float(0x00800000u);  // f32 tiny

  for (int t = 0; t < 3; ++t) {
    // --- parallel sum(min_sq) over 256 slots (zeros pad) ---
    if (tid < 256) {
      float v = minsq[tid];
      #pragma unroll
      for (int m = 1; m < 64; m <<= 1) v += __shfl_xor(v, m);
      if (lane == 0) wred[wv] = v;
    }
    __syncthreads();
    if (tid == 0) ssum = ((wred[0] + wred[1]) + (wred[2] + wred[3])) + 1e-8f;
    __syncthreads();

    // --- z_i = gumbel_i + log(prob_i + 1e-12); argmax (first occurrence) ---
    if (tid < 256) {
      float z = -1e30f;
      if (tid < n) {
        float prob  = minsq[tid] / ssum;
        float logit = logf(prob + 1e-12f);
        uint32_t y0, y1;
        tf2x32(skey[t][0], skey[t][1], 0u, (uint32_t)tid, y0, y1);
        uint32_t bits = y0 ^ y1;
        float f = __uint_as_float((bits >> 9) | 0x3F800000u) - 1.0f;
        float u = (f > 0.f) ? f : TINY;
        z = -logf(-logf(u)) + logit;
      }
      float bv = z; int bi = tid;
      #pragma unroll
      for (int m = 1; m < 64; m <<= 1) {
        float ov = __shfl_xor(bv, m);
        int   oi = __shfl_xor(bi, m);
        if (ov > bv || (ov == bv && oi < bi)) { bv = ov; bi = oi; }
      }
      if (lane == 0) { wmaxv[wv] = bv; wmaxi[wv] = bi; }
    }
    __syncthreads();
    if (tid == 0) {
      float cv = wmaxv[0]; int ci = wmaxi[0];
      for (int w2 = 1; w2 < 4; ++w2)
        if (wmaxv[w2] > cv || (wmaxv[w2] == cv && wmaxi[w2] < ci)) { cv = wmaxv[w2]; ci = wmaxi[w2]; }
      sidx = ci;
    }
    __syncthreads();

    // --- new center from owners' registers -> LDS + out ---
    if (row == sidx) {
      float4* cb = csh4 + part * 48;
      float4* op = (float4*)(ob + (size_t)(t + 1) * D_ + part * 192);
      #pragma unroll
      for (int k = 0; k < 48; ++k) { cb[k] = xr[k]; op[k] = xr[k]; }
    }
    __syncthreads();

    // --- min_sq = min(min_sq, ||x - c||^2) ---
    if (row < n) {
      float acc = 0.f;
      #pragma unroll
      for (int k = 0; k < 48; ++k) {
        float4 c4 = csh4[part * 48 + k];
        float dx = xr[k].x - c4.x, dy = xr[k].y - c4.y;
        float dz = xr[k].z - c4.z, dw = xr[k].w - c4.w;
        acc += dx * dx; acc += dy * dy; acc += dz * dz; acc += dw * dw;
      }
      acc += __shfl_xor(acc, 1);
      if (part == 0) minsq[row] = fminf(minsq[row], acc);
    }
    __syncthreads();
  }
}

extern "C" void kernel_launch(void* const* d_in, const int* in_sizes, int n_in,
                              void* d_out, int out_size, void* d_ws, size_t ws_size,
                              hipStream_t stream) {
  const float* feats = (const float*)d_in[0];
  float* out = (float*)d_out;
  float* ws  = (float*)d_ws;   // uses 12,582,912 bytes (w16 only)

  pool16_kernel<<<3072, 256, 0, stream>>>(feats, ws);
  kmeans_kernel<<<96, 512, 0, stream>>>(ws, out);
}

// Round 6
// 65.717 us; speedup vs baseline: 1.9431x; 1.1335x over previous
//
#include <hip/hip_runtime.h>
#include <stdint.h>

#define D_ 384
#define NPTS 4096
// ws layout (floats): w4 [32*16*384] @0, w8 [32*64*384] @196608, w16 [32*256*384] @983040
#define W4_OFF 0
#define W8_OFF 196608
#define W16_OFF 983040

// ---------------- Threefry-2x32 (JAX-exact, 20 rounds) ----------------
__device__ __forceinline__ void tf_round(uint32_t& x0, uint32_t& x1, int r) {
  x0 += x1;
  x1 = (x1 << r) | (x1 >> (32 - r));
  x1 ^= x0;
}

__device__ void tf2x32(uint32_t k0, uint32_t k1, uint32_t x0, uint32_t x1,
                       uint32_t& y0, uint32_t& y1) {
  uint32_t ks2 = k0 ^ k1 ^ 0x1BD11BDAu;
  x0 += k0; x1 += k1;
  tf_round(x0, x1, 13); tf_round(x0, x1, 15); tf_round(x0, x1, 26); tf_round(x0, x1, 6);
  x0 += k1; x1 += ks2 + 1u;
  tf_round(x0, x1, 17); tf_round(x0, x1, 29); tf_round(x0, x1, 16); tf_round(x0, x1, 24);
  x0 += ks2; x1 += k0 + 2u;
  tf_round(x0, x1, 13); tf_round(x0, x1, 15); tf_round(x0, x1, 26); tf_round(x0, x1, 6);
  x0 += k0; x1 += k1 + 3u;
  tf_round(x0, x1, 17); tf_round(x0, x1, 29); tf_round(x0, x1, 16); tf_round(x0, x1, 24);
  x0 += k1; x1 += ks2 + 4u;
  tf_round(x0, x1, 13); tf_round(x0, x1, 15); tf_round(x0, x1, 26); tf_round(x0, x1, 6);
  x0 += ks2; x1 += k0 + 5u;
  y0 = x0; y1 = x1;
}

// ---------------- pool16: w16[b][cell][d] = mean of 4x4 block ----------------
// blockDim = (96,4): q = threadIdx.x (no div/mod), 4 cells per block.
// Grid 2048 blocks: b = blk/64, cell = (blk%64)*4 + ty.
__global__ __launch_bounds__(384) void pool16_kernel(const float* __restrict__ feats,
                                                     float* __restrict__ ws) {
  int blk = blockIdx.x;
  int b = blk >> 6;
  int cell = ((blk & 63) << 2) + threadIdx.y;
  int q = threadIdx.x;                 // 0..95
  int ch = cell >> 4, cw = cell & 15;
  const float* fb = feats + (size_t)b * NPTS * D_;
  float ax = 0.f, ay = 0.f, az = 0.f, aw = 0.f;
  #pragma unroll
  for (int dh = 0; dh < 4; ++dh) {
    int h = ch * 4 + dh;
    #pragma unroll
    for (int dw = 0; dw < 4; ++dw) {
      int w = cw * 4 + dw;
      float4 v = *(const float4*)(fb + ((size_t)(h * 64 + w)) * D_ + q * 4);
      ax += v.x; ay += v.y; az += v.z; aw += v.w;
    }
  }
  float4 o = { ax * (1.f/16.f), ay * (1.f/16.f), az * (1.f/16.f), aw * (1.f/16.f) };
  *(float4*)(ws + W16_OFF + ((size_t)(b * 256 + cell)) * D_ + q * 4) = o;
}

// ---------------- pool_rest: w8 AND w4 in one launch (both from w16) ----------------
// threads [0, 196608): w8 = mean of 4 w16 cells (association: ((v0+v1)+v2)+v3).
// threads [196608, 245760): w4 via nested pool8->pool4 association (bit-exact
// to the sequential pool8-then-pool4 pipeline; verified rounds 4/5).
__global__ __launch_bounds__(256) void pool_rest_kernel(float* __restrict__ ws) {
  int gid = blockIdx.x * 256 + threadIdx.x;
  if (gid < 196608) {
    int q = gid % 96;
    int c8 = (gid / 96) & 63;
    int b = gid / (96 * 64);
    int p = c8 >> 3, r = c8 & 7;
    const float4* w16b = (const float4*)(ws + W16_OFF + (size_t)b * 256 * D_);
    float ax = 0.f, ay = 0.f, az = 0.f, aw = 0.f;
    #pragma unroll
    for (int a = 0; a < 2; ++a)
      #pragma unroll
      for (int c = 0; c < 2; ++c) {
        int cell = (p * 2 + a) * 16 + (r * 2 + c);
        float4 v = w16b[(size_t)cell * 96 + q];
        ax += v.x; ay += v.y; az += v.z; aw += v.w;
      }
    float4 o = { ax * 0.25f, ay * 0.25f, az * 0.25f, aw * 0.25f };
    *(float4*)(ws + W8_OFF + ((size_t)(b * 64 + c8)) * D_ + q * 4) = o;
  } else {
    int idx = gid - 196608;            // 0..49151
    int q = idx % 96;
    int c4 = (idx / 96) & 15;
    int b = idx / (96 * 16);
    int p = c4 >> 2, r = c4 & 3;
    const float4* w16b = (const float4*)(ws + W16_OFF + (size_t)b * 256 * D_);
    float ax = 0.f, ay = 0.f, az = 0.f, aw = 0.f;   // w4 accum
    #pragma unroll
    for (int a = 0; a < 2; ++a)
      #pragma unroll
      for (int c = 0; c < 2; ++c) {
        int p8 = p * 2 + a, r8 = r * 2 + c;
        float bx = 0.f, by = 0.f, bz = 0.f, bw = 0.f; // w8 accum (fresh, like pool8)
        #pragma unroll
        for (int a2 = 0; a2 < 2; ++a2)
          #pragma unroll
          for (int c2 = 0; c2 < 2; ++c2) {
            int cell = (p8 * 2 + a2) * 16 + (r8 * 2 + c2);
            float4 v = w16b[(size_t)cell * 96 + q];
            bx += v.x; by += v.y; bz += v.z; bw += v.w;
          }
        bx *= 0.25f; by *= 0.25f; bz *= 0.25f; bw *= 0.25f;
        ax += bx; ay += by; az += bz; aw += bw;
      }
    float4 o = { ax * 0.25f, ay * 0.25f, az * 0.25f, aw * 0.25f };
    *(float4*)(ws + W4_OFF + ((size_t)(b * 16 + c4)) * D_ + q * 4) = o;
  }
}

// ---------------- k-means++ seeding (round-3 proven version) ----------------
// 96 blocks (si = blk/32, b = blk%32), 512 threads. 2 threads per row, each
// holding 48 float4 of its row in VGPRs. ALL xr loops fully unrolled (rule #20).
__global__ __launch_bounds__(512) void kmeans_kernel(const float* __restrict__ ws,
                                                     float* __restrict__ out) {
  int blk = blockIdx.x;
  int si = blk / 32;
  int b  = blk % 32;
  int n  = (si == 0) ? 16 : (si == 1) ? 64 : 256;

  const float* pooled;
  if (si == 0)      pooled = ws + W4_OFF  + (size_t)b * 16  * D_;
  else if (si == 1) pooled = ws + W8_OFF  + (size_t)b * 64  * D_;
  else              pooled = ws + W16_OFF + (size_t)b * 256 * D_;
  float* ob = out + ((size_t)b * 12 + si * 4) * D_;

  __shared__ __align__(16) float4 csh4[96];   // one center row
  __shared__ float minsq[256];
  __shared__ uint32_t skey[3][2];
  __shared__ int sidx;
  __shared__ float ssum;
  __shared__ float wred[4];
  __shared__ float wmaxv[4];
  __shared__ int   wmaxi[4];

  int tid  = threadIdx.x;
  int row  = tid >> 1;        // 0..255
  int part = tid & 1;         // half-row owner
  int lane = tid & 63;
  int wv   = tid >> 6;

  if (tid == 0) {
    // base = key(42); folded = fold_in(base, si); bkey = split(folded,32)[b]
    uint32_t f0, f1, bk0, bk1;
    tf2x32(0u, 42u, 0u, (uint32_t)si, f0, f1);
    tf2x32(f0, f1, 0u, (uint32_t)b, bk0, bk1);
    uint32_t k00, k01, k10, k11;
    tf2x32(bk0, bk1, 0u, 0u, k00, k01);     // k0 = split(bkey)[0]
    tf2x32(bk0, bk1, 0u, 1u, k10, k11);     // k1 = split(bkey)[1]
    // randint(k0,(),0,n): _, kk2 = split(k0); lower = bits(kk2); idx = lower % n
    uint32_t q0, q1, l0, l1;
    tf2x32(k00, k01, 0u, 1u, q0, q1);
    tf2x32(q0, q1, 0u, 0u, l0, l1);
    sidx = (int)((l0 ^ l1) & (uint32_t)(n - 1));
    for (int t = 0; t < 3; ++t) {           // step keys = split(k1, 3)
      uint32_t a, bb;
      tf2x32(k10, k11, 0u, (uint32_t)t, a, bb);
      skey[t][0] = a; skey[t][1] = bb;
    }
  }
  if (tid < 256) minsq[tid] = 0.f;

  // load this thread's half-row into registers (contiguous 768B per thread)
  float4 xr[48];
  if (row < n) {
    const float4* rp = (const float4*)(pooled + (size_t)row * D_ + part * 192);
    #pragma unroll
    for (int k = 0; k < 48; ++k) xr[k] = rp[k];
  }
  __syncthreads();   // sidx + minsq ready

  // c0: owners write their registers to LDS + output slot 0
  if (row == sidx) {
    float4* cb = csh4 + part * 48;
    float4* op = (float4*)(ob + part * 192);
    #pragma unroll
    for (int k = 0; k < 48; ++k) { cb[k] = xr[k]; op[k] = xr[k]; }
  }
  __syncthreads();

  // min_sq = ||x - c0||^2
  if (row < n) {
    float acc = 0.f;
    #pragma unroll
    for (int k = 0; k < 48; ++k) {
      float4 c4 = csh4[part * 48 + k];
      float dx = xr[k].x - c4.x, dy = xr[k].y - c4.y;
      float dz = xr[k].z - c4.z, dw = xr[k].w - c4.w;
      acc += dx * dx; acc += dy * dy; acc += dz * dz; acc += dw * dw;
    }
    acc += __shfl_xor(acc, 1);              // combine the 2 half-rows
    if (part == 0) minsq[row] = acc;
  }
  __syncthreads();

  const float TINY = __uint_as_float(0x00800000u);  // f32 tiny

  for (int t = 0; t < 3; ++t) {
    // --- parallel sum(min_sq) over 256 slots (zeros pad) ---
    if (tid < 256) {
      float v = minsq[tid];
      #pragma unroll
      for (int m = 1; m < 64; m <<= 1) v += __shfl_xor(v, m);
      if (lane == 0) wred[wv] = v;
    }
    __syncthreads();
    if (tid == 0) ssum = ((wred[0] + wred[1]) + (wred[2] + wred[3])) + 1e-8f;
    __syncthreads();

    // --- z_i = gumbel_i + log(prob_i + 1e-12); argmax (first occurrence) ---
    if (tid < 256) {
      float z = -1e30f;
      if (tid < n) {
        float prob  = minsq[tid] / ssum;
        float logit = logf(prob + 1e-12f);
        uint32_t y0, y1;
        tf2x32(skey[t][0], skey[t][1], 0u, (uint32_t)tid, y0, y1);
        uint32_t bits = y0 ^ y1;
        float f = __uint_as_float((bits >> 9) | 0x3F800000u) - 1.0f;
        float u = (f > 0.f) ? f : TINY;
        z = -logf(-logf(u)) + logit;
      }
      float bv = z; int bi = tid;
      #pragma unroll
      for (int m = 1; m < 64; m <<= 1) {
        float ov = __shfl_xor(bv, m);
        int   oi = __shfl_xor(bi, m);
        if (ov > bv || (ov == bv && oi < bi)) { bv = ov; bi = oi; }
      }
      if (lane == 0) { wmaxv[wv] = bv; wmaxi[wv] = bi; }
    }
    __syncthreads();
    if (tid == 0) {
      float cv = wmaxv[0]; int ci = wmaxi[0];
      for (int w2 = 1; w2 < 4; ++w2)
        if (wmaxv[w2] > cv || (wmaxv[w2] == cv && wmaxi[w2] < ci)) { cv = wmaxv[w2]; ci = wmaxi[w2]; }
      sidx = ci;
    }
    __syncthreads();

    // --- new center from owners' registers -> LDS + out ---
    if (row == sidx) {
      float4* cb = csh4 + part * 48;
      float4* op = (float4*)(ob + (size_t)(t + 1) * D_ + part * 192);
      #pragma unroll
      for (int k = 0; k < 48; ++k) { cb[k] = xr[k]; op[k] = xr[k]; }
    }
    __syncthreads();

    // --- min_sq = min(min_sq, ||x - c||^2) ---
    if (row < n) {
      float acc = 0.f;
      #pragma unroll
      for (int k = 0; k < 48; ++k) {
        float4 c4 = csh4[part * 48 + k];
        float dx = xr[k].x - c4.x, dy = xr[k].y - c4.y;
        float dz = xr[k].z - c4.z, dw = xr[k].w - c4.w;
        acc += dx * dx; acc += dy * dy; acc += dz * dz; acc += dw * dw;
      }
      acc += __shfl_xor(acc, 1);
      if (part == 0) minsq[row] = fminf(minsq[row], acc);
    }
    __syncthreads();
  }
}

extern "C" void kernel_launch(void* const* d_in, const int* in_sizes, int n_in,
                              void* d_out, int out_size, void* d_ws, size_t ws_size,
                              hipStream_t stream) {
  const float* feats = (const float*)d_in[0];
  float* out = (float*)d_out;
  float* ws  = (float*)d_ws;   // uses 16,515,072 bytes

  pool16_kernel<<<2048, dim3(96, 4, 1), 0, stream>>>(feats, ws);
  pool_rest_kernel<<<960, 256, 0, stream>>>(ws);
  kmeans_kernel<<<96, 512, 0, stream>>>(ws, out);
}